// Round 1
// baseline (1031.137 us; speedup 1.0000x reference)
//
#include <hip/hip_runtime.h>

#define B_ 32
#define N_ 1024
#define M_ 256
#define D_ 512

// ---- workspace layout (float offsets) ----
#define OFF_S    ((size_t)0)                      // B*N*M = 8388608
#define OFF_A    ((size_t)8388608)                // B*N*M
#define OFF_Q2C  ((size_t)16777216)               // B*M*D = 4194304
#define OFF_CDOT ((size_t)20971520)               // B*N   = 32768
#define OFF_QDOT ((size_t)21004288)               // B*M   = 8192
#define OFF_RMAX ((size_t)21012480)               // B*N
#define OFF_RSUM ((size_t)21045248)               // B*N
#define OFF_CMAX ((size_t)21078016)               // B*M
#define OFF_CSUM ((size_t)21086208)               // B*M
#define OFF_PMAX ((size_t)21094400)               // B*16*M = 131072
#define OFF_PSUM ((size_t)21225472)               // B*16*M

__global__ __launch_bounds__(256) void dots_kernel(
    const float* __restrict__ ctx, const float* __restrict__ qry,
    const float* __restrict__ w, float* __restrict__ cdot, float* __restrict__ qdot)
{
    int row  = blockIdx.x * 4 + (threadIdx.x >> 6);
    int lane = threadIdx.x & 63;
    const float* src; const float* wp; float* dst;
    if (row < B_ * N_) {
        src = ctx + (size_t)row * D_; wp = w + D_;      // w_c = w[D:2D]
        dst = cdot + row;
    } else {
        int rr = row - B_ * N_;
        src = qry + (size_t)rr * D_; wp = w;            // w_q = w[0:D]
        dst = qdot + rr;
    }
    float s = 0.f;
#pragma unroll
    for (int i = 0; i < D_ / 64; ++i)
        s = fmaf(src[lane + 64 * i], wp[lane + 64 * i], s);
#pragma unroll
    for (int off = 32; off; off >>= 1) s += __shfl_down(s, off, 64);
    if (lane == 0) *dst = s;
}

// S[b,n,m] = cdot[b,n] + qdot[b,m] + sum_d ctx[b,n,d]*w_m[d]*qry[b,m,d]
__global__ __launch_bounds__(256) void s_gemm(
    const float* __restrict__ ctx, const float* __restrict__ qry,
    const float* __restrict__ w, const float* __restrict__ cdot,
    const float* __restrict__ qdot, float* __restrict__ S)
{
    const int b = blockIdx.z;
    const int n0 = blockIdx.y * 64;
    const int m0 = blockIdx.x * 64;
    const float* Ap = ctx + (size_t)b * N_ * D_;
    const float* Bp = qry + (size_t)b * M_ * D_;
    const float* wm = w + 2 * D_;
    __shared__ float As[16][65];
    __shared__ float Bs[16][65];
    const int tid = threadIdx.x;
    const int tx = tid & 15, ty = tid >> 4;
    float acc[4][4] = {};
    for (int k0 = 0; k0 < D_; k0 += 16) {
#pragma unroll
        for (int i = 0; i < 4; ++i) {
            int idx = tid + i * 256;
            int rl = idx >> 4, kl = idx & 15;
            As[kl][rl] = Ap[(size_t)(n0 + rl) * D_ + k0 + kl] * wm[k0 + kl];
            Bs[kl][rl] = Bp[(size_t)(m0 + rl) * D_ + k0 + kl];
        }
        __syncthreads();
#pragma unroll
        for (int k = 0; k < 16; ++k) {
            float a[4], bb[4];
#pragma unroll
            for (int i = 0; i < 4; ++i) a[i] = As[k][ty * 4 + i];
#pragma unroll
            for (int j = 0; j < 4; ++j) bb[j] = Bs[k][tx * 4 + j];
#pragma unroll
            for (int i = 0; i < 4; ++i)
#pragma unroll
                for (int j = 0; j < 4; ++j)
                    acc[i][j] = fmaf(a[i], bb[j], acc[i][j]);
        }
        __syncthreads();
    }
#pragma unroll
    for (int i = 0; i < 4; ++i) {
        int n = n0 + ty * 4 + i;
        float cd = cdot[b * N_ + n];
        size_t rowoff = ((size_t)b * N_ + n) * M_;
#pragma unroll
        for (int j = 0; j < 4; ++j) {
            int m = m0 + tx * 4 + j;
            S[rowoff + m] = acc[i][j] + cd + qdot[b * M_ + m];
        }
    }
}

__global__ __launch_bounds__(256) void row_stats(
    const float* __restrict__ S, const int* __restrict__ q_mask,
    float* __restrict__ rmax, float* __restrict__ rsum)
{
    int row  = blockIdx.x * 4 + (threadIdx.x >> 6);   // b*N + n
    int lane = threadIdx.x & 63;
    int b = row >> 10;                                // N = 1024
    const float* Sp = S + (size_t)row * M_;
    const int* qm = q_mask + b * M_;
    float v[4];
    float mx = -1e30f;
#pragma unroll
    for (int i = 0; i < 4; ++i) {
        int m = lane + 64 * i;
        float x = qm[m] ? Sp[m] : -1e9f;
        v[i] = x; mx = fmaxf(mx, x);
    }
#pragma unroll
    for (int off = 32; off; off >>= 1) mx = fmaxf(mx, __shfl_down(mx, off, 64));
    mx = __shfl(mx, 0, 64);
    float sm = 0.f;
#pragma unroll
    for (int i = 0; i < 4; ++i) sm += __expf(v[i] - mx);
#pragma unroll
    for (int off = 32; off; off >>= 1) sm += __shfl_down(sm, off, 64);
    if (lane == 0) { rmax[row] = mx; rsum[row] = sm; }
}

// partial column stats: chunk of 64 n's, one thread per m
__global__ __launch_bounds__(256) void col_stats_part(
    const float* __restrict__ S, const int* __restrict__ c_mask,
    float* __restrict__ pmax, float* __restrict__ psum)
{
    int b = blockIdx.y, ch = blockIdx.x, m = threadIdx.x;
    const float* Sp = S + ((size_t)b * N_ + ch * 64) * M_;
    const int* cm = c_mask + b * N_ + ch * 64;
    float mx = -1e30f, sm = 0.f;
    for (int n = 0; n < 64; ++n) {
        float x = cm[n] ? Sp[(size_t)n * M_ + m] : -1e9f;
        if (x > mx) { sm = sm * __expf(mx - x) + 1.f; mx = x; }
        else        { sm += __expf(x - mx); }
    }
    pmax[((size_t)b * 16 + ch) * M_ + m] = mx;
    psum[((size_t)b * 16 + ch) * M_ + m] = sm;
}

__global__ __launch_bounds__(256) void col_stats_combine(
    const float* __restrict__ pmax, const float* __restrict__ psum,
    float* __restrict__ cmax, float* __restrict__ csum)
{
    int idx = blockIdx.x * 256 + threadIdx.x;  // b*M + m
    int b = idx >> 8, m = idx & 255;
    float mx = -1e30f;
#pragma unroll
    for (int ch = 0; ch < 16; ++ch)
        mx = fmaxf(mx, pmax[((size_t)b * 16 + ch) * M_ + m]);
    float sm = 0.f;
#pragma unroll
    for (int ch = 0; ch < 16; ++ch)
        sm += psum[((size_t)b * 16 + ch) * M_ + m] *
              __expf(pmax[((size_t)b * 16 + ch) * M_ + m] - mx);
    cmax[idx] = mx; csum[idx] = sm;
}

// A = rowsoftmax(S, q_mask) -> Abuf ; Bm = colsoftmax(S, c_mask) -> S (in place)
__global__ __launch_bounds__(256) void normalize_kernel(
    float* __restrict__ S, float* __restrict__ Abuf,
    const int* __restrict__ q_mask, const int* __restrict__ c_mask,
    const float* __restrict__ rmax, const float* __restrict__ rsum,
    const float* __restrict__ cmax, const float* __restrict__ csum)
{
    size_t idx = (size_t)blockIdx.x * 256 + threadIdx.x;
    int m = (int)(idx & 255);
    size_t bn = idx >> 8;
    int n = (int)(bn & 1023);
    int b = (int)(bn >> 10);
    float s = S[idx];
    float a  = q_mask[b * M_ + m] ? __expf(s - rmax[bn]) / rsum[bn] : 0.f;
    float bm = c_mask[b * N_ + n] ? __expf(s - cmax[b * M_ + m]) / csum[b * M_ + m] : 0.f;
    Abuf[idx] = a;
    S[idx] = bm;
}

// c2q = A(N,M) @ qry(M,D); writes out chunks 0,1,2
__global__ __launch_bounds__(256) void c2q_gemm(
    const float* __restrict__ Abuf, const float* __restrict__ qry,
    const float* __restrict__ ctx, float* __restrict__ out)
{
    const int b = blockIdx.z;
    const int n0 = blockIdx.y * 64;
    const int d0 = blockIdx.x * 64;
    const float* Ap = Abuf + (size_t)b * N_ * M_;
    const float* Bp = qry + (size_t)b * M_ * D_;
    __shared__ float As[16][65];
    __shared__ float Bs[16][65];
    const int tid = threadIdx.x;
    const int tx = tid & 15, ty = tid >> 4;
    float acc[4][4] = {};
    for (int k0 = 0; k0 < M_; k0 += 16) {
#pragma unroll
        for (int i = 0; i < 4; ++i) {
            int idx = tid + i * 256;
            int rl = idx >> 4, kl = idx & 15;
            As[kl][rl] = Ap[(size_t)(n0 + rl) * M_ + k0 + kl];
            int dl = idx & 63, kl2 = idx >> 6;
            Bs[kl2][dl] = Bp[(size_t)(k0 + kl2) * D_ + d0 + dl];
        }
        __syncthreads();
#pragma unroll
        for (int k = 0; k < 16; ++k) {
            float a[4], bb[4];
#pragma unroll
            for (int i = 0; i < 4; ++i) a[i] = As[k][ty * 4 + i];
#pragma unroll
            for (int j = 0; j < 4; ++j) bb[j] = Bs[k][tx * 4 + j];
#pragma unroll
            for (int i = 0; i < 4; ++i)
#pragma unroll
                for (int j = 0; j < 4; ++j)
                    acc[i][j] = fmaf(a[i], bb[j], acc[i][j]);
        }
        __syncthreads();
    }
#pragma unroll
    for (int i = 0; i < 4; ++i) {
        int n = n0 + ty * 4 + i;
        size_t base = (size_t)b * N_ + n;
#pragma unroll
        for (int j = 0; j < 4; ++j) {
            int d = d0 + tx * 4 + j;
            float c = ctx[base * D_ + d];
            float v = acc[i][j];
            size_t o = base * (4 * D_) + d;
            out[o] = c;
            out[o + D_] = v;
            out[o + 2 * D_] = c * v;
        }
    }
}

// Q2C[m,d] = sum_n Bm[n,m] * ctx[n,d]   (Bm stored n-major in S buffer)
__global__ __launch_bounds__(256) void q2c_part_gemm(
    const float* __restrict__ Bm, const float* __restrict__ ctx,
    float* __restrict__ Q2C)
{
    const int b = blockIdx.z;
    const int m0 = blockIdx.y * 64;
    const int d0 = blockIdx.x * 64;
    const float* Ap = Bm + (size_t)b * N_ * M_;   // [N][M]
    const float* Bp = ctx + (size_t)b * N_ * D_;  // [N][D]
    __shared__ float As[16][65];
    __shared__ float Bs[16][65];
    const int tid = threadIdx.x;
    const int tx = tid & 15, ty = tid >> 4;
    float acc[4][4] = {};
    for (int k0 = 0; k0 < N_; k0 += 16) {
#pragma unroll
        for (int i = 0; i < 4; ++i) {
            int idx = tid + i * 256;
            int ml = idx & 63, kl = idx >> 6;
            As[kl][ml] = Ap[(size_t)(k0 + kl) * M_ + m0 + ml];
            Bs[kl][ml] = Bp[(size_t)(k0 + kl) * D_ + d0 + ml];
        }
        __syncthreads();
#pragma unroll
        for (int k = 0; k < 16; ++k) {
            float a[4], bb[4];
#pragma unroll
            for (int i = 0; i < 4; ++i) a[i] = As[k][ty * 4 + i];
#pragma unroll
            for (int j = 0; j < 4; ++j) bb[j] = Bs[k][tx * 4 + j];
#pragma unroll
            for (int i = 0; i < 4; ++i)
#pragma unroll
                for (int j = 0; j < 4; ++j)
                    acc[i][j] = fmaf(a[i], bb[j], acc[i][j]);
        }
        __syncthreads();
    }
#pragma unroll
    for (int i = 0; i < 4; ++i) {
        int m = m0 + ty * 4 + i;
#pragma unroll
        for (int j = 0; j < 4; ++j) {
            int d = d0 + tx * 4 + j;
            Q2C[((size_t)b * M_ + m) * D_ + d] = acc[i][j];
        }
    }
}

// q2c = A(N,M) @ Q2C(M,D); writes out chunk 3 = ctx * q2c
__global__ __launch_bounds__(256) void q2c_gemm(
    const float* __restrict__ Abuf, const float* __restrict__ Q2C,
    const float* __restrict__ ctx, float* __restrict__ out)
{
    const int b = blockIdx.z;
    const int n0 = blockIdx.y * 64;
    const int d0 = blockIdx.x * 64;
    const float* Ap = Abuf + (size_t)b * N_ * M_;
    const float* Bp = Q2C + (size_t)b * M_ * D_;
    __shared__ float As[16][65];
    __shared__ float Bs[16][65];
    const int tid = threadIdx.x;
    const int tx = tid & 15, ty = tid >> 4;
    float acc[4][4] = {};
    for (int k0 = 0; k0 < M_; k0 += 16) {
#pragma unroll
        for (int i = 0; i < 4; ++i) {
            int idx = tid + i * 256;
            int rl = idx >> 4, kl = idx & 15;
            As[kl][rl] = Ap[(size_t)(n0 + rl) * M_ + k0 + kl];
            int dl = idx & 63, kl2 = idx >> 6;
            Bs[kl2][dl] = Bp[(size_t)(k0 + kl2) * D_ + d0 + dl];
        }
        __syncthreads();
#pragma unroll
        for (int k = 0; k < 16; ++k) {
            float a[4], bb[4];
#pragma unroll
            for (int i = 0; i < 4; ++i) a[i] = As[k][ty * 4 + i];
#pragma unroll
            for (int j = 0; j < 4; ++j) bb[j] = Bs[k][tx * 4 + j];
#pragma unroll
            for (int i = 0; i < 4; ++i)
#pragma unroll
                for (int j = 0; j < 4; ++j)
                    acc[i][j] = fmaf(a[i], bb[j], acc[i][j]);
        }
        __syncthreads();
    }
#pragma unroll
    for (int i = 0; i < 4; ++i) {
        int n = n0 + ty * 4 + i;
        size_t base = (size_t)b * N_ + n;
#pragma unroll
        for (int j = 0; j < 4; ++j) {
            int d = d0 + tx * 4 + j;
            float c = ctx[base * D_ + d];
            out[base * (4 * D_) + 3 * D_ + d] = c * acc[i][j];
        }
    }
}

extern "C" void kernel_launch(void* const* d_in, const int* in_sizes, int n_in,
                              void* d_out, int out_size, void* d_ws, size_t ws_size,
                              hipStream_t stream) {
    const float* ctx   = (const float*)d_in[0];
    const float* qry   = (const float*)d_in[1];
    const int*   cmask = (const int*)d_in[2];
    const int*   qmask = (const int*)d_in[3];
    const float* w     = (const float*)d_in[4];
    float* out = (float*)d_out;
    float* ws  = (float*)d_ws;

    float* S    = ws + OFF_S;
    float* Abuf = ws + OFF_A;
    float* Q2C  = ws + OFF_Q2C;
    float* cdot = ws + OFF_CDOT;
    float* qdot = ws + OFF_QDOT;
    float* rmax = ws + OFF_RMAX;
    float* rsum = ws + OFF_RSUM;
    float* cmx  = ws + OFF_CMAX;
    float* csm  = ws + OFF_CSUM;
    float* pmax = ws + OFF_PMAX;
    float* psum = ws + OFF_PSUM;

    dots_kernel<<<(B_ * N_ + B_ * M_) / 4, 256, 0, stream>>>(ctx, qry, w, cdot, qdot);

    dim3 gS(M_ / 64, N_ / 64, B_);
    s_gemm<<<gS, 256, 0, stream>>>(ctx, qry, w, cdot, qdot, S);

    row_stats<<<B_ * N_ / 4, 256, 0, stream>>>(S, qmask, rmax, rsum);

    dim3 gC(16, B_);
    col_stats_part<<<gC, 256, 0, stream>>>(S, cmask, pmax, psum);
    col_stats_combine<<<B_ * M_ / 256, 256, 0, stream>>>(pmax, psum, cmx, csm);

    normalize_kernel<<<(B_ * N_ * M_) / 256, 256, 0, stream>>>(
        S, Abuf, qmask, cmask, rmax, rsum, cmx, csm);

    dim3 g1(D_ / 64, N_ / 64, B_);
    c2q_gemm<<<g1, 256, 0, stream>>>(Abuf, qry, ctx, out);

    dim3 g2(D_ / 64, M_ / 64, B_);
    q2c_part_gemm<<<g2, 256, 0, stream>>>(S, ctx, Q2C);

    q2c_gemm<<<g1, 256, 0, stream>>>(Abuf, Q2C, ctx, out);
}

// Round 2
// 534.350 us; speedup vs baseline: 1.9297x; 1.9297x over previous
//
#include <hip/hip_runtime.h>
#include <hip/hip_bf16.h>

#define B_ 32
#define N_ 1024
#define M_ 256
#define D_ 512

typedef __attribute__((ext_vector_type(8))) short short8;
typedef __attribute__((ext_vector_type(4))) float f32x4;

// ---- workspace layout (float offsets), total 29745152 floats = 119 MB ----
#define OFF_S     ((size_t)0)          // fp32 S, B*N*M
#define OFF_CTXW  ((size_t)8388608)    // bf16 ctx*w_m [B][N][D]  (dead after s_gemm)
#define OFF_ANM   ((size_t)8388608)    // bf16 A [B][N][M]  (overlays ctxw)
#define OFF_BMT   ((size_t)12582912)   // bf16 Bm^T [B][M][N] (overlays ctxw 2nd half)
#define OFF_QB    ((size_t)16777216)   // bf16 qry [B][M][D]; Q2CT overlays after s_gemm
#define OFF_QT    ((size_t)18874368)   // bf16 qry^T [B][D][M]
#define OFF_CT    ((size_t)20971520)   // bf16 ctx^T [B][D][N]
#define OFF_CDOT  ((size_t)29360128)
#define OFF_QDOT  ((size_t)29392896)
#define OFF_RMAX  ((size_t)29401088)
#define OFF_RSUM  ((size_t)29433856)
#define OFF_CMAX  ((size_t)29466624)
#define OFF_CSUM  ((size_t)29474816)
#define OFF_PMAX  ((size_t)29483008)
#define OFF_PSUM  ((size_t)29614080)

// ---------------- prep: casts / transposes ----------------

__global__ __launch_bounds__(256) void prep_ctxw(
    const float* __restrict__ ctx, const float* __restrict__ w,
    __hip_bfloat16* __restrict__ ctxw)
{
    size_t i4 = ((size_t)blockIdx.x * 256 + threadIdx.x) * 4;
    int d = (int)(i4 & (D_ - 1));
    float4 c = *(const float4*)(ctx + i4);
    float4 wm = *(const float4*)(w + 2 * D_ + d);
    __hip_bfloat16 o[4] __attribute__((aligned(8)));
    o[0] = __float2bfloat16(c.x * wm.x);
    o[1] = __float2bfloat16(c.y * wm.y);
    o[2] = __float2bfloat16(c.z * wm.z);
    o[3] = __float2bfloat16(c.w * wm.w);
    *(ushort4*)(ctxw + i4) = *(ushort4*)o;
}

__global__ __launch_bounds__(256) void prep_qry(
    const float* __restrict__ qry, __hip_bfloat16* __restrict__ qb)
{
    size_t i4 = ((size_t)blockIdx.x * 256 + threadIdx.x) * 4;
    float4 c = *(const float4*)(qry + i4);
    __hip_bfloat16 o[4] __attribute__((aligned(8)));
    o[0] = __float2bfloat16(c.x);
    o[1] = __float2bfloat16(c.y);
    o[2] = __float2bfloat16(c.z);
    o[3] = __float2bfloat16(c.w);
    *(ushort4*)(qb + i4) = *(ushort4*)o;
}

// src [B][rows][cols] fp32 -> dst [B][cols][rows] bf16
__global__ __launch_bounds__(256) void transpose_cast(
    const float* __restrict__ src, __hip_bfloat16* __restrict__ dst,
    int rows, int cols)
{
    __shared__ float t[64][65];
    int b = blockIdx.z, r0 = blockIdx.y * 64, c0 = blockIdx.x * 64;
    int tr = threadIdx.x >> 6, tc = threadIdx.x & 63;
    const float* sp = src + ((size_t)b * rows + r0) * cols + c0;
#pragma unroll
    for (int i = 0; i < 16; ++i)
        t[tr + i * 4][tc] = sp[(size_t)(tr + i * 4) * cols + tc];
    __syncthreads();
    __hip_bfloat16* dp = dst + ((size_t)b * cols + c0) * rows + r0;
#pragma unroll
    for (int i = 0; i < 16; ++i)
        dp[(size_t)(tr + i * 4) * rows + tc] = __float2bfloat16(t[tc][tr + i * 4]);
}

__global__ __launch_bounds__(256) void dots_kernel(
    const float* __restrict__ ctx, const float* __restrict__ qry,
    const float* __restrict__ w, float* __restrict__ cdot, float* __restrict__ qdot)
{
    int row  = blockIdx.x * 4 + (threadIdx.x >> 6);
    int lane = threadIdx.x & 63;
    const float* src; const float* wp; float* dst;
    if (row < B_ * N_) {
        src = ctx + (size_t)row * D_; wp = w + D_;
        dst = cdot + row;
    } else {
        int rr = row - B_ * N_;
        src = qry + (size_t)rr * D_; wp = w;
        dst = qdot + rr;
    }
    float s = 0.f;
#pragma unroll
    for (int i = 0; i < D_ / 64; ++i)
        s = fmaf(src[lane + 64 * i], wp[lane + 64 * i], s);
#pragma unroll
    for (int off = 32; off; off >>= 1) s += __shfl_down(s, off, 64);
    if (lane == 0) *dst = s;
}

// ---------------- MFMA 128x128 tile core ----------------

__device__ __forceinline__ void gl2lds16(const __hip_bfloat16* g, __hip_bfloat16* l) {
    __builtin_amdgcn_global_load_lds(
        (const __attribute__((address_space(1))) unsigned int*)g,
        (__attribute__((address_space(3))) unsigned int*)l, 16, 0, 0);
}

// A: [128 rows][K] row-major bf16, B: [128 cols][K] row-major bf16.
// acc[fi][fj] += A_tile * B_tile^T over K.
template<int KTOT>
__device__ __forceinline__ void mfma128(
    const __hip_bfloat16* __restrict__ Abase, int lda,
    const __hip_bfloat16* __restrict__ Bbase, int ldb,
    __hip_bfloat16* As, __hip_bfloat16* Bs, f32x4 acc[4][4])
{
    const int tid = threadIdx.x;
    const int w = tid >> 6, lane = tid & 63;
    const int quad = lane >> 4, lr = lane & 15;
    const int wr = w >> 1, wc = w & 1;
    const int srow = w * 32 + (lane >> 2);
    const int scol = (lane & 3) * 8;
    const __hip_bfloat16* ga0 = Abase + (size_t)srow * lda + scol;
    const __hip_bfloat16* ga1 = ga0 + (size_t)16 * lda;
    const __hip_bfloat16* gb0 = Bbase + (size_t)srow * ldb + scol;
    const __hip_bfloat16* gb1 = gb0 + (size_t)16 * ldb;
    __hip_bfloat16* la0 = As + w * 1024;
    __hip_bfloat16* la1 = As + w * 1024 + 512;
    __hip_bfloat16* lb0 = Bs + w * 1024;
    __hip_bfloat16* lb1 = Bs + w * 1024 + 512;
    const int aoff = (wr * 64 + lr) * 32 + quad * 8;
    const int boff = (wc * 64 + lr) * 32 + quad * 8;

    for (int k0 = 0; k0 < KTOT; k0 += 32) {
        gl2lds16(ga0, la0); gl2lds16(ga1, la1);
        gl2lds16(gb0, lb0); gl2lds16(gb1, lb1);
        ga0 += 32; ga1 += 32; gb0 += 32; gb1 += 32;
        asm volatile("s_waitcnt vmcnt(0)" ::: "memory");
        __syncthreads();
        short8 a[4], bb[4];
        const short8* ap = (const short8*)(As + aoff);
        const short8* bp = (const short8*)(Bs + boff);
#pragma unroll
        for (int fi = 0; fi < 4; ++fi) a[fi] = ap[fi * 64];
#pragma unroll
        for (int fj = 0; fj < 4; ++fj) bb[fj] = bp[fj * 64];
#pragma unroll
        for (int fi = 0; fi < 4; ++fi)
#pragma unroll
            for (int fj = 0; fj < 4; ++fj)
                acc[fi][fj] = __builtin_amdgcn_mfma_f32_16x16x32_bf16(
                    a[fi], bb[fj], acc[fi][fj], 0, 0, 0);
        __syncthreads();
    }
}

#define ACC_INIT f32x4 acc[4][4]; \
    _Pragma("unroll") for (int i = 0; i < 4; ++i) \
    _Pragma("unroll") for (int j = 0; j < 4; ++j) acc[i][j] = (f32x4){0.f, 0.f, 0.f, 0.f};

#define EPI_IDX const int tid = threadIdx.x, lane = tid & 63, quad = lane >> 4, lr = lane & 15; \
    const int wr = tid >> 7, wc = (tid >> 6) & 1;

// S[n][m] = ctxw[n][:] . qry[m][:] + cdot[n] + qdot[m]
__global__ __launch_bounds__(256) void s_gemm_mfma(
    const __hip_bfloat16* __restrict__ ctxw, const __hip_bfloat16* __restrict__ qryb,
    const float* __restrict__ cdot, const float* __restrict__ qdot,
    float* __restrict__ S)
{
    __shared__ __align__(16) __hip_bfloat16 As[4096], Bs[4096];
    const int b = blockIdx.z, n0 = blockIdx.y * 128, m0 = blockIdx.x * 128;
    ACC_INIT
    mfma128<512>(ctxw + ((size_t)b * N_ + n0) * D_, D_,
                 qryb + ((size_t)b * M_ + m0) * D_, D_, As, Bs, acc);
    EPI_IDX
#pragma unroll
    for (int fi = 0; fi < 4; ++fi) {
#pragma unroll
        for (int r = 0; r < 4; ++r) {
            int n = n0 + wr * 64 + fi * 16 + quad * 4 + r;
            float cd = cdot[b * N_ + n];
            size_t rowoff = ((size_t)b * N_ + n) * M_;
#pragma unroll
            for (int fj = 0; fj < 4; ++fj) {
                int m = m0 + wc * 64 + fj * 16 + lr;
                S[rowoff + m] = acc[fi][fj][r] + cd + qdot[b * M_ + m];
            }
        }
    }
}

// Q2CT[d][m] = sum_n ctxT[d][n] * BmT[m][n]
__global__ __launch_bounds__(256) void q2cpart_mfma(
    const __hip_bfloat16* __restrict__ ctxT, const __hip_bfloat16* __restrict__ BmT,
    __hip_bfloat16* __restrict__ Q2CT)
{
    __shared__ __align__(16) __hip_bfloat16 As[4096], Bs[4096];
    const int b = blockIdx.z, d0 = blockIdx.y * 128, m0 = blockIdx.x * 128;
    ACC_INIT
    mfma128<1024>(ctxT + ((size_t)b * D_ + d0) * N_, N_,
                  BmT + ((size_t)b * M_ + m0) * N_, N_, As, Bs, acc);
    EPI_IDX
#pragma unroll
    for (int fi = 0; fi < 4; ++fi) {
#pragma unroll
        for (int r = 0; r < 4; ++r) {
            int d = d0 + wr * 64 + fi * 16 + quad * 4 + r;
#pragma unroll
            for (int fj = 0; fj < 4; ++fj) {
                int m = m0 + wc * 64 + fj * 16 + lr;
                Q2CT[((size_t)b * D_ + d) * M_ + m] = __float2bfloat16(acc[fi][fj][r]);
            }
        }
    }
}

// c2q[n][d] = sum_m A[n][m] qryT[d][m]; writes out chunks 0,1,2
__global__ __launch_bounds__(256) void c2q_mfma(
    const __hip_bfloat16* __restrict__ Anm, const __hip_bfloat16* __restrict__ qryT,
    const float* __restrict__ ctx, float* __restrict__ out)
{
    __shared__ __align__(16) __hip_bfloat16 As[4096], Bs[4096];
    const int b = blockIdx.z, n0 = blockIdx.y * 128, d0 = blockIdx.x * 128;
    ACC_INIT
    mfma128<256>(Anm + ((size_t)b * N_ + n0) * M_, M_,
                 qryT + ((size_t)b * D_ + d0) * M_, M_, As, Bs, acc);
    EPI_IDX
#pragma unroll
    for (int fi = 0; fi < 4; ++fi) {
#pragma unroll
        for (int r = 0; r < 4; ++r) {
            int n = n0 + wr * 64 + fi * 16 + quad * 4 + r;
            size_t ibase = ((size_t)b * N_ + n) * D_;
            size_t obase = ((size_t)b * N_ + n) * (4 * D_);
#pragma unroll
            for (int fj = 0; fj < 4; ++fj) {
                int d = d0 + wc * 64 + fj * 16 + lr;
                float c = ctx[ibase + d];
                float v = acc[fi][fj][r];
                out[obase + d] = c;
                out[obase + D_ + d] = v;
                out[obase + 2 * D_ + d] = c * v;
            }
        }
    }
}

// q2c[n][d] = sum_m A[n][m] Q2CT[d][m]; writes out chunk 3 = ctx*q2c
__global__ __launch_bounds__(256) void q2c_mfma(
    const __hip_bfloat16* __restrict__ Anm, const __hip_bfloat16* __restrict__ Q2CT,
    const float* __restrict__ ctx, float* __restrict__ out)
{
    __shared__ __align__(16) __hip_bfloat16 As[4096], Bs[4096];
    const int b = blockIdx.z, n0 = blockIdx.y * 128, d0 = blockIdx.x * 128;
    ACC_INIT
    mfma128<256>(Anm + ((size_t)b * N_ + n0) * M_, M_,
                 Q2CT + ((size_t)b * D_ + d0) * M_, M_, As, Bs, acc);
    EPI_IDX
#pragma unroll
    for (int fi = 0; fi < 4; ++fi) {
#pragma unroll
        for (int r = 0; r < 4; ++r) {
            int n = n0 + wr * 64 + fi * 16 + quad * 4 + r;
            size_t ibase = ((size_t)b * N_ + n) * D_;
            size_t obase = ((size_t)b * N_ + n) * (4 * D_);
#pragma unroll
            for (int fj = 0; fj < 4; ++fj) {
                int d = d0 + wc * 64 + fj * 16 + lr;
                out[obase + 3 * D_ + d] = ctx[ibase + d] * acc[fi][fj][r];
            }
        }
    }
}

// ---------------- softmax statistics (fp32 on S) ----------------

__global__ __launch_bounds__(256) void row_stats(
    const float* __restrict__ S, const int* __restrict__ q_mask,
    float* __restrict__ rmax, float* __restrict__ rsum)
{
    int row  = blockIdx.x * 4 + (threadIdx.x >> 6);
    int lane = threadIdx.x & 63;
    int b = row >> 10;
    const float* Sp = S + (size_t)row * M_;
    const int* qm = q_mask + b * M_;
    float v[4];
    float mx = -1e30f;
#pragma unroll
    for (int i = 0; i < 4; ++i) {
        int m = lane + 64 * i;
        float x = qm[m] ? Sp[m] : -1e9f;
        v[i] = x; mx = fmaxf(mx, x);
    }
#pragma unroll
    for (int off = 32; off; off >>= 1) mx = fmaxf(mx, __shfl_down(mx, off, 64));
    mx = __shfl(mx, 0, 64);
    float sm = 0.f;
#pragma unroll
    for (int i = 0; i < 4; ++i) sm += __expf(v[i] - mx);
#pragma unroll
    for (int off = 32; off; off >>= 1) sm += __shfl_down(sm, off, 64);
    if (lane == 0) { rmax[row] = mx; rsum[row] = sm; }
}

__global__ __launch_bounds__(256) void col_stats_part(
    const float* __restrict__ S, const int* __restrict__ c_mask,
    float* __restrict__ pmax, float* __restrict__ psum)
{
    int b = blockIdx.y, ch = blockIdx.x, m = threadIdx.x;
    const float* Sp = S + ((size_t)b * N_ + ch * 64) * M_;
    const int* cm = c_mask + b * N_ + ch * 64;
    float mx = -1e30f, sm = 0.f;
    for (int n = 0; n < 64; ++n) {
        float x = cm[n] ? Sp[(size_t)n * M_ + m] : -1e9f;
        if (x > mx) { sm = sm * __expf(mx - x) + 1.f; mx = x; }
        else        { sm += __expf(x - mx); }
    }
    pmax[((size_t)b * 16 + ch) * M_ + m] = mx;
    psum[((size_t)b * 16 + ch) * M_ + m] = sm;
}

__global__ __launch_bounds__(256) void col_stats_combine(
    const float* __restrict__ pmax, const float* __restrict__ psum,
    float* __restrict__ cmax, float* __restrict__ csum)
{
    int idx = blockIdx.x * 256 + threadIdx.x;
    int b = idx >> 8, m = idx & 255;
    float mx = -1e30f;
#pragma unroll
    for (int ch = 0; ch < 16; ++ch)
        mx = fmaxf(mx, pmax[((size_t)b * 16 + ch) * M_ + m]);
    float sm = 0.f;
#pragma unroll
    for (int ch = 0; ch < 16; ++ch)
        sm += psum[((size_t)b * 16 + ch) * M_ + m] *
              __expf(pmax[((size_t)b * 16 + ch) * M_ + m] - mx);
    cmax[idx] = mx; csum[idx] = sm;
}

// A -> Anm (bf16, [n][m]); Bm -> BmT (bf16, [m][n] via LDS transpose)
__global__ __launch_bounds__(256) void normalize_kernel(
    const float* __restrict__ S, __hip_bfloat16* __restrict__ Anm,
    __hip_bfloat16* __restrict__ BmT,
    const int* __restrict__ q_mask, const int* __restrict__ c_mask,
    const float* __restrict__ rmax, const float* __restrict__ rsum,
    const float* __restrict__ cmax, const float* __restrict__ csum)
{
    __shared__ float t[64][65];
    int b = blockIdx.z, n0 = blockIdx.y * 64, m0 = blockIdx.x * 64;
    int tr = threadIdx.x >> 6, tc = threadIdx.x & 63;
    int m = m0 + tc;
    int qm = q_mask[b * M_ + m];
    float cmx = cmax[b * M_ + m], csm = csum[b * M_ + m];
#pragma unroll
    for (int i = 0; i < 16; ++i) {
        int n = n0 + tr + i * 4;
        size_t idx = ((size_t)b * N_ + n) * M_ + m;
        float s = S[idx];
        float a  = qm ? __expf(s - rmax[b * N_ + n]) / rsum[b * N_ + n] : 0.f;
        float bm = c_mask[b * N_ + n] ? __expf(s - cmx) / csm : 0.f;
        Anm[idx] = __float2bfloat16(a);
        t[tc][tr + i * 4] = bm;
    }
    __syncthreads();
#pragma unroll
    for (int i = 0; i < 16; ++i) {
        int ml = tr + i * 4;
        BmT[((size_t)b * M_ + m0 + ml) * N_ + n0 + tc] = __float2bfloat16(t[ml][tc]);
    }
}

extern "C" void kernel_launch(void* const* d_in, const int* in_sizes, int n_in,
                              void* d_out, int out_size, void* d_ws, size_t ws_size,
                              hipStream_t stream) {
    const float* ctx   = (const float*)d_in[0];
    const float* qry   = (const float*)d_in[1];
    const int*   cmask = (const int*)d_in[2];
    const int*   qmask = (const int*)d_in[3];
    const float* w     = (const float*)d_in[4];
    float* out = (float*)d_out;
    float* ws  = (float*)d_ws;

    float* S = ws + OFF_S;
    __hip_bfloat16* ctxw = (__hip_bfloat16*)(ws + OFF_CTXW);
    __hip_bfloat16* Anm  = (__hip_bfloat16*)(ws + OFF_ANM);
    __hip_bfloat16* BmT  = (__hip_bfloat16*)(ws + OFF_BMT);
    __hip_bfloat16* qb   = (__hip_bfloat16*)(ws + OFF_QB);
    __hip_bfloat16* Q2CT = (__hip_bfloat16*)(ws + OFF_QB);
    __hip_bfloat16* qT   = (__hip_bfloat16*)(ws + OFF_QT);
    __hip_bfloat16* cT   = (__hip_bfloat16*)(ws + OFF_CT);
    float* cdot = ws + OFF_CDOT;
    float* qdot = ws + OFF_QDOT;
    float* rmax = ws + OFF_RMAX;
    float* rsum = ws + OFF_RSUM;
    float* cmx  = ws + OFF_CMAX;
    float* csm  = ws + OFF_CSUM;
    float* pmax = ws + OFF_PMAX;
    float* psum = ws + OFF_PSUM;

    prep_ctxw<<<B_ * N_ * D_ / 1024, 256, 0, stream>>>(ctx, w, ctxw);
    prep_qry<<<B_ * M_ * D_ / 1024, 256, 0, stream>>>(qry, qb);
    dim3 gtc(D_ / 64, N_ / 64, B_);
    transpose_cast<<<gtc, 256, 0, stream>>>(ctx, cT, N_, D_);
    dim3 gtq(D_ / 64, M_ / 64, B_);
    transpose_cast<<<gtq, 256, 0, stream>>>(qry, qT, M_, D_);
    dots_kernel<<<(B_ * N_ + B_ * M_) / 4, 256, 0, stream>>>(ctx, qry, w, cdot, qdot);

    dim3 gS(M_ / 128, N_ / 128, B_);
    s_gemm_mfma<<<gS, 256, 0, stream>>>(ctxw, qb, cdot, qdot, S);

    row_stats<<<B_ * N_ / 4, 256, 0, stream>>>(S, qmask, rmax, rsum);
    dim3 gC(16, B_);
    col_stats_part<<<gC, 256, 0, stream>>>(S, cmask, pmax, psum);
    col_stats_combine<<<B_ * M_ / 256, 256, 0, stream>>>(pmax, psum, cmx, csm);

    dim3 gN(M_ / 64, N_ / 64, B_);
    normalize_kernel<<<gN, 256, 0, stream>>>(S, Anm, BmT, qmask, cmask,
                                             rmax, rsum, cmx, csm);

    dim3 gP(M_ / 128, D_ / 128, B_);
    q2cpart_mfma<<<gP, 256, 0, stream>>>(cT, BmT, Q2CT);

    dim3 gO(D_ / 128, N_ / 128, B_);
    c2q_mfma<<<gO, 256, 0, stream>>>(Anm, qT, ctx, out);
    q2c_mfma<<<gO, 256, 0, stream>>>(Anm, Q2CT, ctx, out);
}